// Round 1
// baseline (1584.476 us; speedup 1.0000x reference)
//
#include <hip/hip_runtime.h>

#define D_IN   128
#define HEADS  8
#define FOUT   64
#define NOUT   16   // 8 src + 8 trg folded outputs

// ---------------------------------------------------------------------------
// Detect whether edge_index arrived as int32 or int64 (little-endian).
// If int64, every odd 32-bit word within the first `nwords` words (= the
// high halves of the src row) is zero. For int32 data those words are real
// node indices (uniform in [0,100000)) and are almost surely not all zero.
// flag == 0  ->  int64 layout ; flag != 0 -> int32 layout.
__global__ void k_detect(const unsigned int* __restrict__ idx_w, int nwords,
                         unsigned int* __restrict__ flag) {
    unsigned int local = 0;
    int stride = gridDim.x * blockDim.x;
    for (int i = blockIdx.x * blockDim.x + threadIdx.x; 2 * i + 1 < nwords; i += stride)
        local |= idx_w[2 * i + 1];
    if (__any(local != 0) && (threadIdx.x & 63) == 0)
        atomicOr(flag, 1u);
}

// ---------------------------------------------------------------------------
// Fold scoring vectors into the projection:
//   Wc[h      ][d] = sum_f W[d, h*64+f] * a_src[h,f]
//   Wc[h + 8  ][d] = sum_f W[d, h*64+f] * a_trg[h,f]
// Layout Wc is [16][128] (transposed) so k_scores lanes read stride-1.
__global__ void k_fold_w(const float* __restrict__ W,
                         const float* __restrict__ a_src,
                         const float* __restrict__ a_trg,
                         float* __restrict__ Wc) {
    int t = blockIdx.x * blockDim.x + threadIdx.x;
    if (t >= D_IN * HEADS) return;
    int d = t >> 3, h = t & 7;
    const float* wrow = W + d * (HEADS * FOUT) + h * FOUT;
    float s1 = 0.f, s2 = 0.f;
    #pragma unroll 4
    for (int f = 0; f < FOUT; ++f) {
        float w = wrow[f];
        s1 += w * a_src[h * FOUT + f];
        s2 += w * a_trg[h * FOUT + f];
    }
    Wc[h * D_IN + d]              = s1;
    Wc[(HEADS + h) * D_IN + d]    = s2;
}

// ---------------------------------------------------------------------------
// Per-node scores: one wave per node.  Lane l holds x[n,l] and x[n,64+l];
// the 16 folded weight columns live in registers (hoisted out of the node
// loop).  16 butterfly reductions across the wave, lanes 0..15 write out.
__global__ void k_scores(const float* __restrict__ x,
                         const float* __restrict__ Wc,
                         float* __restrict__ ssrc,
                         float* __restrict__ strg, int N) {
    int lane   = threadIdx.x & 63;
    int wid    = blockIdx.x * (blockDim.x >> 6) + (threadIdx.x >> 6);
    int nwaves = gridDim.x * (blockDim.x >> 6);

    float w1[NOUT], w2[NOUT];
    #pragma unroll
    for (int o = 0; o < NOUT; ++o) {
        w1[o] = Wc[o * D_IN + lane];
        w2[o] = Wc[o * D_IN + 64 + lane];
    }

    for (int n = wid; n < N; n += nwaves) {
        float x1 = x[(size_t)n * D_IN + lane];
        float x2 = x[(size_t)n * D_IN + 64 + lane];
        float acc[NOUT];
        #pragma unroll
        for (int o = 0; o < NOUT; ++o)
            acc[o] = x1 * w1[o] + x2 * w2[o];
        #pragma unroll
        for (int o = 0; o < NOUT; ++o) {
            #pragma unroll
            for (int s = 32; s; s >>= 1)
                acc[o] += __shfl_xor(acc[o], s, 64);
        }
        if (lane < HEADS)           ssrc[(size_t)n * HEADS + lane]          = acc[lane];
        else if (lane < 2 * HEADS)  strg[(size_t)n * HEADS + (lane - HEADS)] = acc[lane];
    }
}

__device__ __forceinline__ void load_edge(const unsigned int* idx, int e, int E,
                                          bool is64, unsigned int& s, unsigned int& t) {
    if (is64) { s = idx[2 * (size_t)e]; t = idx[2 * ((size_t)E + e)]; }
    else      { s = idx[e];             t = idx[(size_t)E + e]; }
}

__device__ __forceinline__ void edge_scores(const float* ssrc, const float* strg,
                                            unsigned int s, unsigned int t, float* ex) {
    const float4* sp = (const float4*)(ssrc + (size_t)s * HEADS);
    const float4* tp = (const float4*)(strg + (size_t)t * HEADS);
    float4 sa = sp[0], sb = sp[1], ta = tp[0], tb = tp[1];
    float v[8] = { sa.x + ta.x, sa.y + ta.y, sa.z + ta.z, sa.w + ta.w,
                   sb.x + tb.x, sb.y + tb.y, sb.z + tb.z, sb.w + tb.w };
    #pragma unroll
    for (int h = 0; h < HEADS; ++h) {
        float sc = v[h];
        sc = sc > 0.f ? sc : 0.2f * sc;   // LeakyReLU(0.2)
        ex[h] = expf(sc);                 // no max-subtraction: |s| <~ 7, safe in fp32
    }
}

// Edge pass 1: accumulate per-(target,head) exp sums.
__global__ void k_edge_sum(const unsigned int* __restrict__ idx, int E,
                           const float* __restrict__ ssrc,
                           const float* __restrict__ strg,
                           float* __restrict__ sums,
                           const unsigned int* __restrict__ flag) {
    int e = blockIdx.x * blockDim.x + threadIdx.x;
    if (e >= E) return;
    bool is64 = (*flag == 0u);
    unsigned int s, t;
    load_edge(idx, e, E, is64, s, t);
    float ex[8];
    edge_scores(ssrc, strg, s, t, ex);
    float* dst = sums + (size_t)t * HEADS;
    #pragma unroll
    for (int h = 0; h < HEADS; ++h)
        atomicAdd(dst + h, ex[h]);
}

// Edge pass 2: recompute exp (cheaper than storing 102 MB) and normalize.
__global__ void k_edge_out(const unsigned int* __restrict__ idx, int E,
                           const float* __restrict__ ssrc,
                           const float* __restrict__ strg,
                           const float* __restrict__ sums,
                           const unsigned int* __restrict__ flag,
                           float* __restrict__ out) {
    int e = blockIdx.x * blockDim.x + threadIdx.x;
    if (e >= E) return;
    bool is64 = (*flag == 0u);
    unsigned int s, t;
    load_edge(idx, e, E, is64, s, t);
    float ex[8];
    edge_scores(ssrc, strg, s, t, ex);
    const float4* sm = (const float4*)(sums + (size_t)t * HEADS);
    float4 m0 = sm[0], m1 = sm[1];
    float4 o0, o1;
    o0.x = ex[0] / (m0.x + 1e-16f);  o0.y = ex[1] / (m0.y + 1e-16f);
    o0.z = ex[2] / (m0.z + 1e-16f);  o0.w = ex[3] / (m0.w + 1e-16f);
    o1.x = ex[4] / (m1.x + 1e-16f);  o1.y = ex[5] / (m1.y + 1e-16f);
    o1.z = ex[6] / (m1.z + 1e-16f);  o1.w = ex[7] / (m1.w + 1e-16f);
    float4* op = (float4*)(out + (size_t)e * HEADS);
    op[0] = o0;
    op[1] = o1;
}

// ---------------------------------------------------------------------------
extern "C" void kernel_launch(void* const* d_in, const int* in_sizes, int n_in,
                              void* d_out, int out_size, void* d_ws, size_t ws_size,
                              hipStream_t stream) {
    const float*        x     = (const float*)d_in[0];
    const float*        W     = (const float*)d_in[1];
    const float*        a_src = (const float*)d_in[2];
    const float*        a_trg = (const float*)d_in[3];
    const unsigned int* idx   = (const unsigned int*)d_in[4];

    const int N = in_sizes[0] / D_IN;        // 100000
    const int E = in_sizes[4] / 2;           // 3200000 (element count, dtype-agnostic)

    float* out = (float*)d_out;

    // workspace layout
    char*  ws        = (char*)d_ws;
    size_t sums_b    = (size_t)N * HEADS * sizeof(float);
    float*        sums = (float*)ws;
    unsigned int* flag = (unsigned int*)(ws + sums_b);
    float*        ssrc = (float*)(ws + sums_b + 64);
    float*        strg = (float*)(ws + sums_b + 64 + sums_b);
    float*        Wc   = (float*)(ws + sums_b + 64 + 2 * sums_b);

    // zero the atomic-sum region + detection flag (harness does not re-poison)
    hipMemsetAsync(ws, 0, sums_b + 64, stream);

    k_detect <<<1024, 256, 0, stream>>>(idx, in_sizes[4], flag);
    k_fold_w <<<(D_IN * HEADS + 255) / 256, 256, 0, stream>>>(W, a_src, a_trg, Wc);
    k_scores <<<2048, 256, 0, stream>>>(x, Wc, ssrc, strg, N);

    int eblocks = (E + 255) / 256;
    k_edge_sum <<<eblocks, 256, 0, stream>>>(idx, E, ssrc, strg, sums, flag);
    k_edge_out <<<eblocks, 256, 0, stream>>>(idx, E, ssrc, strg, sums, flag, out);
}